// Round 1
// baseline (800.291 us; speedup 1.0000x reference)
//
#include <hip/hip_runtime.h>

#define DIM 128

typedef __attribute__((ext_vector_type(8))) short short8;
typedef __attribute__((ext_vector_type(4))) float f32x4;

// round-to-nearest-even fp32 -> bf16 bit pattern
__device__ __forceinline__ unsigned short f2bf(float f) {
    union { float f; unsigned u; } v; v.f = f;
    unsigned u = v.u;
    return (unsigned short)((u + 0x7FFFu + ((u >> 16) & 1u)) >> 16);
}

__device__ __forceinline__ short8 cvt8(f32x4 lo, f32x4 hi) {
    short8 r;
    r[0] = (short)f2bf(lo[0]); r[1] = (short)f2bf(lo[1]);
    r[2] = (short)f2bf(lo[2]); r[3] = (short)f2bf(lo[3]);
    r[4] = (short)f2bf(hi[0]); r[5] = (short)f2bf(hi[1]);
    r[6] = (short)f2bf(hi[2]); r[7] = (short)f2bf(hi[3]);
    return r;
}

// Weight prep: W1 [512,128] f32 -> W1t [128,512] bf16 ; W2 [128,128] f32 -> W2t [128,128] bf16
__global__ void prep_weights(const float* __restrict__ W1, const float* __restrict__ W2,
                             unsigned short* __restrict__ W1t, unsigned short* __restrict__ W2t) {
    int tid = blockIdx.x * blockDim.x + threadIdx.x;
    if (tid < 512 * 128) {
        int n = tid >> 9;         // 0..127
        int k = tid & 511;        // 0..511
        W1t[tid] = f2bf(W1[k * 128 + n]);
    } else if (tid < 512 * 128 + 128 * 128) {
        int t = tid - 512 * 128;
        int n = t >> 7;
        int k = t & 127;
        W2t[t] = f2bf(W2[k * 128 + n]);
    }
}

// One K=128 chunk of phase-1 GEMM for this wave's 32-row strip.
__device__ __forceinline__ void chunk_gemm(const float* p0, const float* p1,
                                           const unsigned short* __restrict__ wchunk,
                                           int quad, int l16, f32x4 acc[2][8]) {
#pragma unroll
    for (int s = 0; s < 4; ++s) {
        const int kl = s * 32 + quad * 8;
        f32x4 a0lo = *(const f32x4*)(p0 + kl);
        f32x4 a0hi = *(const f32x4*)(p0 + kl + 4);
        f32x4 a1lo = *(const f32x4*)(p1 + kl);
        f32x4 a1hi = *(const f32x4*)(p1 + kl + 4);
        short8 a0 = cvt8(a0lo, a0hi);
        short8 a1 = cvt8(a1lo, a1hi);
#pragma unroll
        for (int nt = 0; nt < 8; ++nt) {
            short8 b = *(const short8*)(wchunk + (nt * 16 + l16) * 512 + kl);
            acc[0][nt] = __builtin_amdgcn_mfma_f32_16x16x32_bf16(a0, b, acc[0][nt], 0, 0, 0);
            acc[1][nt] = __builtin_amdgcn_mfma_f32_16x16x32_bf16(a1, b, acc[1][nt], 0, 0, 0);
        }
    }
}

__global__ __launch_bounds__(256, 2)
void megnet_edge(const float* __restrict__ src, const float* __restrict__ dst,
                 const float* __restrict__ edge_attr, const float* __restrict__ u,
                 const int* __restrict__ batch,
                 const unsigned short* __restrict__ W1t, const unsigned short* __restrict__ W2t,
                 const float* __restrict__ b1, const float* __restrict__ b2,
                 float* __restrict__ out, int E) {
    // per-wave 32x128 bf16 h-buffer, 16B-granule xor-swizzled: 8 KiB per wave
    __shared__ unsigned char lds_raw[4 * 32 * 256];

    const int tid  = threadIdx.x;
    const int wave = tid >> 6;
    const int lane = tid & 63;
    const int quad = lane >> 4;
    const int l16  = lane & 15;

    const long rowBase = (long)blockIdx.x * 128 + wave * 32;
    if (rowBase >= E) return;

    // bias fragments (col = nt*16 + l16)
    float b1r[8], b2r[8];
#pragma unroll
    for (int nt = 0; nt < 8; ++nt) {
        b1r[nt] = b1[nt * 16 + l16];
        b2r[nt] = b2[nt * 16 + l16];
    }

    // u-gather rows for the two 16-row A tiles
    const long ar0 = rowBase + l16;
    const long ar1 = rowBase + 16 + l16;
    const int ub0 = batch[ar0];
    const int ub1 = batch[ar1];

    f32x4 acc[2][8];
#pragma unroll
    for (int mt = 0; mt < 2; ++mt)
#pragma unroll
        for (int nt = 0; nt < 8; ++nt) acc[mt][nt] = (f32x4)0.0f;

    // ---- Phase 1: h = relu(concat @ W1 + b1) ----
    chunk_gemm(src + ar0 * DIM,       src + ar1 * DIM,       W1t + 0 * 128, quad, l16, acc);
    chunk_gemm(dst + ar0 * DIM,       dst + ar1 * DIM,       W1t + 1 * 128, quad, l16, acc);
    chunk_gemm(edge_attr + ar0 * DIM, edge_attr + ar1 * DIM, W1t + 2 * 128, quad, l16, acc);
    chunk_gemm(u + (long)ub0 * DIM,   u + (long)ub1 * DIM,   W1t + 3 * 128, quad, l16, acc);

    // epilogue -> swizzled LDS (C-layout -> A-layout transform)
    unsigned char* myLds = lds_raw + wave * 32 * 256;
#pragma unroll
    for (int mt = 0; mt < 2; ++mt)
#pragma unroll
        for (int nt = 0; nt < 8; ++nt)
#pragma unroll
            for (int r = 0; r < 4; ++r) {
                const int lr = mt * 16 + quad * 4 + r;      // local edge row 0..31
                const int cc = nt * 16 + l16;               // h column 0..127
                float h = acc[mt][nt][r] + b1r[nt];
                h = h > 0.0f ? h : 0.0f;
                const int g = (cc >> 3) ^ (lr & 7);
                *(unsigned short*)(myLds + lr * 256 + g * 16 + (cc & 7) * 2) = f2bf(h);
            }
    __syncthreads();  // also orders LDS writes before reads within the wave

    // ---- Phase 2: out = h @ W2 + b2 ----
    f32x4 acc2[2][8];
#pragma unroll
    for (int mt = 0; mt < 2; ++mt)
#pragma unroll
        for (int nt = 0; nt < 8; ++nt) acc2[mt][nt] = (f32x4)0.0f;

#pragma unroll
    for (int s = 0; s < 4; ++s) {
        const int kl = s * 32 + quad * 8;
        const int g  = kl >> 3;  // 16B granule index
        const int lr0 = l16;
        const int lr1 = 16 + l16;
        short8 a0 = *(const short8*)(myLds + lr0 * 256 + ((g ^ (lr0 & 7)) * 16));
        short8 a1 = *(const short8*)(myLds + lr1 * 256 + ((g ^ (lr1 & 7)) * 16));
#pragma unroll
        for (int nt = 0; nt < 8; ++nt) {
            short8 b = *(const short8*)(W2t + (nt * 16 + l16) * 128 + kl);
            acc2[0][nt] = __builtin_amdgcn_mfma_f32_16x16x32_bf16(a0, b, acc2[0][nt], 0, 0, 0);
            acc2[1][nt] = __builtin_amdgcn_mfma_f32_16x16x32_bf16(a1, b, acc2[1][nt], 0, 0, 0);
        }
    }

    // store
#pragma unroll
    for (int mt = 0; mt < 2; ++mt)
#pragma unroll
        for (int nt = 0; nt < 8; ++nt)
#pragma unroll
            for (int r = 0; r < 4; ++r) {
                const long row = rowBase + mt * 16 + quad * 4 + r;
                const int col = nt * 16 + l16;
                out[row * DIM + col] = acc2[mt][nt][r] + b2r[nt];
            }
}

extern "C" void kernel_launch(void* const* d_in, const int* in_sizes, int n_in,
                              void* d_out, int out_size, void* d_ws, size_t ws_size,
                              hipStream_t stream) {
    const float* src       = (const float*)d_in[0];
    const float* dst       = (const float*)d_in[1];
    const float* edge_attr = (const float*)d_in[2];
    const float* u         = (const float*)d_in[3];
    const int*   batch     = (const int*)d_in[4];
    const float* W1        = (const float*)d_in[5];
    const float* b1        = (const float*)d_in[6];
    const float* W2        = (const float*)d_in[7];
    const float* b2        = (const float*)d_in[8];
    float* out             = (float*)d_out;

    unsigned short* W1t = (unsigned short*)d_ws;           // 512*128 bf16 = 128 KiB
    unsigned short* W2t = W1t + 512 * 128;                 // 128*128 bf16 = 32 KiB

    const int E = in_sizes[0] / DIM;

    prep_weights<<<(512 * 128 + 128 * 128 + 255) / 256, 256, 0, stream>>>(W1, W2, W1t, W2t);
    megnet_edge<<<(E + 127) / 128, 256, 0, stream>>>(src, dst, edge_attr, u, batch,
                                                     W1t, W2t, b1, b2, out, E);
}

// Round 2
// 799.567 us; speedup vs baseline: 1.0009x; 1.0009x over previous
//
#include <hip/hip_runtime.h>

#define DIM 128

typedef __attribute__((ext_vector_type(8))) short short8;
typedef __attribute__((ext_vector_type(4))) float f32x4;

// round-to-nearest-even fp32 -> bf16 bit pattern
__device__ __forceinline__ unsigned short f2bf(float f) {
    union { float f; unsigned u; } v; v.f = f;
    unsigned u = v.u;
    return (unsigned short)((u + 0x7FFFu + ((u >> 16) & 1u)) >> 16);
}

__device__ __forceinline__ short8 cvt8(f32x4 lo, f32x4 hi) {
    short8 r;
    r[0] = (short)f2bf(lo[0]); r[1] = (short)f2bf(lo[1]);
    r[2] = (short)f2bf(lo[2]); r[3] = (short)f2bf(lo[3]);
    r[4] = (short)f2bf(hi[0]); r[5] = (short)f2bf(hi[1]);
    r[6] = (short)f2bf(hi[2]); r[7] = (short)f2bf(hi[3]);
    return r;
}

// Weight prep: W1 [512,128] f32 -> W1t [128,512] bf16 ; W2 [128,128] f32 -> W2t [128,128] bf16
__global__ void prep_weights(const float* __restrict__ W1, const float* __restrict__ W2,
                             unsigned short* __restrict__ W1t, unsigned short* __restrict__ W2t) {
    int tid = blockIdx.x * blockDim.x + threadIdx.x;
    if (tid < 512 * 128) {
        int n = tid >> 9;         // 0..127
        int k = tid & 511;        // 0..511
        W1t[tid] = f2bf(W1[k * 128 + n]);
    } else if (tid < 512 * 128 + 128 * 128) {
        int t = tid - 512 * 128;
        int n = t >> 7;
        int k = t & 127;
        W2t[t] = f2bf(W2[k * 128 + n]);
    }
}

__global__ __launch_bounds__(256, 2)
void megnet_edge(const float* __restrict__ src, const float* __restrict__ dst,
                 const float* __restrict__ edge_attr, const float* __restrict__ u,
                 const int* __restrict__ batch,
                 const unsigned short* __restrict__ W1t, const unsigned short* __restrict__ W2t,
                 const float* __restrict__ b1, const float* __restrict__ b2,
                 float* __restrict__ out, int E) {
    // per-wave 32x128 bf16 h-buffer, 16B-granule xor-swizzled: 8 KiB per wave
    __shared__ unsigned char lds_raw[4 * 32 * 256];

    const int tid  = threadIdx.x;
    const int wave = tid >> 6;
    const int lane = tid & 63;
    const int quad = lane >> 4;
    const int l16  = lane & 15;

    const long rowBase = (long)blockIdx.x * 128 + wave * 32;
    if (rowBase >= E) return;

    const long ar0 = rowBase + l16;
    const long ar1 = ar0 + 16;
    const int ub0 = batch[ar0];
    const int ub1 = batch[ar1];

    const float* rp0[4] = { src + ar0 * DIM, dst + ar0 * DIM, edge_attr + ar0 * DIM, u + (long)ub0 * DIM };
    const float* rp1[4] = { src + ar1 * DIM, dst + ar1 * DIM, edge_attr + ar1 * DIM, u + (long)ub1 * DIM };

    const int koff = quad * 8;   // lane's k base within a 32-wide s-segment

    f32x4 acc[2][8];
#pragma unroll
    for (int mt = 0; mt < 2; ++mt)
#pragma unroll
        for (int nt = 0; nt < 8; ++nt) acc[mt][nt] = (f32x4)0.0f;

    // ---- Phase 1: h = relu(concat @ W1 + b1), chunk-prefetched ----
    // batch-issue ALL 16 A-loads of chunk 0 (16 KB/wave in flight)
    f32x4 raw0[8], raw1[8];
#pragma unroll
    for (int j = 0; j < 8; ++j) {
        const int off = (j >> 1) * 32 + koff + (j & 1) * 4;
        raw0[j] = *(const f32x4*)(rp0[0] + off);
        raw1[j] = *(const f32x4*)(rp1[0] + off);
    }

#pragma unroll
    for (int c = 0; c < 4; ++c) {
        // consume current chunk's raw data, then immediately re-issue loads for chunk c+1
        short8 a0[4], a1[4];
#pragma unroll
        for (int s = 0; s < 4; ++s) a0[s] = cvt8(raw0[2 * s], raw0[2 * s + 1]);
        if (c < 3) {
#pragma unroll
            for (int j = 0; j < 8; ++j) {
                const int off = (j >> 1) * 32 + koff + (j & 1) * 4;
                raw0[j] = *(const f32x4*)(rp0[c + 1] + off);
            }
        }
#pragma unroll
        for (int s = 0; s < 4; ++s) a1[s] = cvt8(raw1[2 * s], raw1[2 * s + 1]);
        if (c < 3) {
#pragma unroll
            for (int j = 0; j < 8; ++j) {
                const int off = (j >> 1) * 32 + koff + (j & 1) * 4;
                raw1[j] = *(const f32x4*)(rp1[c + 1] + off);
            }
        }

        // B-fragments: double-buffered across s-steps (L1/L2-resident weights)
        const unsigned short* wc = W1t + c * 128;
        short8 bn[8];
#pragma unroll
        for (int nt = 0; nt < 8; ++nt)
            bn[nt] = *(const short8*)(wc + (nt * 16 + l16) * 512 + koff);

#pragma unroll
        for (int s = 0; s < 4; ++s) {
            short8 bc[8];
#pragma unroll
            for (int nt = 0; nt < 8; ++nt) bc[nt] = bn[nt];
            if (s < 3) {
#pragma unroll
                for (int nt = 0; nt < 8; ++nt)
                    bn[nt] = *(const short8*)(wc + (nt * 16 + l16) * 512 + (s + 1) * 32 + koff);
            }
#pragma unroll
            for (int nt = 0; nt < 8; ++nt) {
                acc[0][nt] = __builtin_amdgcn_mfma_f32_16x16x32_bf16(a0[s], bc[nt], acc[0][nt], 0, 0, 0);
                acc[1][nt] = __builtin_amdgcn_mfma_f32_16x16x32_bf16(a1[s], bc[nt], acc[1][nt], 0, 0, 0);
            }
        }
    }

    // phase-1 epilogue -> swizzled per-wave LDS (C-layout -> A-layout transform)
    float b1r[8];
#pragma unroll
    for (int nt = 0; nt < 8; ++nt) b1r[nt] = b1[nt * 16 + l16];

    unsigned char* myLds = lds_raw + wave * 32 * 256;
#pragma unroll
    for (int mt = 0; mt < 2; ++mt)
#pragma unroll
        for (int nt = 0; nt < 8; ++nt)
#pragma unroll
            for (int r = 0; r < 4; ++r) {
                const int lr = mt * 16 + quad * 4 + r;      // local edge row 0..31
                const int cc = nt * 16 + l16;               // h column 0..127
                float h = acc[mt][nt][r] + b1r[nt];
                h = h > 0.0f ? h : 0.0f;
                const int g = (cc >> 3) ^ (lr & 7);
                *(unsigned short*)(myLds + lr * 256 + g * 16 + (cc & 7) * 2) = f2bf(h);
            }
    // LDS buffer is wave-private: wave-local drain is sufficient, no block barrier
    asm volatile("s_waitcnt lgkmcnt(0)" ::: "memory");

    // ---- Phase 2: out = h @ W2 + b2 ----
    f32x4 acc2[2][8];
#pragma unroll
    for (int mt = 0; mt < 2; ++mt)
#pragma unroll
        for (int nt = 0; nt < 8; ++nt) acc2[mt][nt] = (f32x4)0.0f;

    // batch all 8 LDS A-frag reads
    short8 ha0[4], ha1[4];
#pragma unroll
    for (int s = 0; s < 4; ++s) {
        const int g = s * 4 + quad;  // 16B granule index of kl = s*32+quad*8
        const int lr0 = l16;
        const int lr1 = 16 + l16;
        ha0[s] = *(const short8*)(myLds + lr0 * 256 + ((g ^ (lr0 & 7)) * 16));
        ha1[s] = *(const short8*)(myLds + lr1 * 256 + ((g ^ (lr1 & 7)) * 16));
    }

    short8 bn2[8];
#pragma unroll
    for (int nt = 0; nt < 8; ++nt)
        bn2[nt] = *(const short8*)(W2t + (nt * 16 + l16) * 128 + koff);

#pragma unroll
    for (int s = 0; s < 4; ++s) {
        short8 bc2[8];
#pragma unroll
        for (int nt = 0; nt < 8; ++nt) bc2[nt] = bn2[nt];
        if (s < 3) {
#pragma unroll
            for (int nt = 0; nt < 8; ++nt)
                bn2[nt] = *(const short8*)(W2t + (nt * 16 + l16) * 128 + (s + 1) * 32 + koff);
        }
#pragma unroll
        for (int nt = 0; nt < 8; ++nt) {
            acc2[0][nt] = __builtin_amdgcn_mfma_f32_16x16x32_bf16(ha0[s], bc2[nt], acc2[0][nt], 0, 0, 0);
            acc2[1][nt] = __builtin_amdgcn_mfma_f32_16x16x32_bf16(ha1[s], bc2[nt], acc2[1][nt], 0, 0, 0);
        }
    }

    // store epilogue
    float b2r[8];
#pragma unroll
    for (int nt = 0; nt < 8; ++nt) b2r[nt] = b2[nt * 16 + l16];

#pragma unroll
    for (int mt = 0; mt < 2; ++mt)
#pragma unroll
        for (int nt = 0; nt < 8; ++nt)
#pragma unroll
            for (int r = 0; r < 4; ++r) {
                const long row = rowBase + mt * 16 + quad * 4 + r;
                const int col = nt * 16 + l16;
                out[row * DIM + col] = acc2[mt][nt][r] + b2r[nt];
            }
}

extern "C" void kernel_launch(void* const* d_in, const int* in_sizes, int n_in,
                              void* d_out, int out_size, void* d_ws, size_t ws_size,
                              hipStream_t stream) {
    const float* src       = (const float*)d_in[0];
    const float* dst       = (const float*)d_in[1];
    const float* edge_attr = (const float*)d_in[2];
    const float* u         = (const float*)d_in[3];
    const int*   batch     = (const int*)d_in[4];
    const float* W1        = (const float*)d_in[5];
    const float* b1        = (const float*)d_in[6];
    const float* W2        = (const float*)d_in[7];
    const float* b2        = (const float*)d_in[8];
    float* out             = (float*)d_out;

    unsigned short* W1t = (unsigned short*)d_ws;           // 512*128 bf16 = 128 KiB
    unsigned short* W2t = W1t + 512 * 128;                 // 128*128 bf16 = 32 KiB

    const int E = in_sizes[0] / DIM;

    prep_weights<<<(512 * 128 + 128 * 128 + 255) / 256, 256, 0, stream>>>(W1, W2, W1t, W2t);
    megnet_edge<<<(E + 127) / 128, 256, 0, stream>>>(src, dst, edge_attr, u, batch,
                                                     W1t, W2t, b1, b2, out, E);
}